// Round 5
// baseline (99.464 us; speedup 1.0000x reference)
//
#include <hip/hip_runtime.h>

#define S_LEN 4096
#define B_SZ 8
#define KTOT 384            // M (256) + D (128)
#define CPROWS 544          // 8-elem rows per parity copy (zero-padded past 4096)
#define HN_OFF 8388608      // 8*4096*256

typedef __attribute__((ext_vector_type(8))) short short8;
typedef __attribute__((ext_vector_type(4))) float f32x4;

typedef const __attribute__((address_space(1))) unsigned int as1_u32;
typedef __attribute__((address_space(3))) unsigned int as3_u32;

__device__ __forceinline__ void gload16(const short* g, short* l) {
  __builtin_amdgcn_global_load_lds((as1_u32*)g, (as3_u32*)l, 16, 0, 0);
}

__device__ __forceinline__ short f2bf(float f) {
  union { float f; unsigned u; } v; v.f = f;
  unsigned r = v.u + 0x7FFFu + ((v.u >> 16) & 1u);
  return (short)(r >> 16);
}

// K1 fused prep:
//  blocks [0,8192):      u = relu(x@W_u+b_u) scattered into 8 parity copies cp;
//                        x -> bf16 into mx[...,256:384]
//  blocks [8192,8264):   zero the e>=4096 tail of cp
//  blocks [8264,12360):  H -> bf16
//  blocks [12360,12744): W_h^T -> bf16
__global__ __launch_bounds__(256) void k_prep(const float* __restrict__ x,
                                              const float* __restrict__ Wu,
                                              const float* __restrict__ bu,
                                              const float* __restrict__ H,
                                              const float* __restrict__ Wh,
                                              short* __restrict__ mx,
                                              short* __restrict__ cp,
                                              short* __restrict__ Hb,
                                              short* __restrict__ wht) {
  int bx = blockIdx.x;
  if (bx >= 12360) {
    int j = (bx - 12360) * 256 + threadIdx.x;
    if (j < 256 * KTOT) {
      int n = j / KTOT, k = j % KTOT;
      wht[j] = f2bf(Wh[k * 256 + n]);
    }
    return;
  }
  if (bx >= 8264) {
    int i = (bx - 8264) * 256 + threadIdx.x;
    Hb[i] = f2bf(H[i]);
    return;
  }
  if (bx >= 8192) {
    int idx = (bx - 8192) * 256 + threadIdx.x;   // b(8)*p(8)*r(36)*j(8)
    if (idx < 18432) {
      int j = idx & 7;
      int r = 508 + ((idx >> 3) % 36);
      int rem = (idx >> 3) / 36;
      int p = rem & 7;
      int b = rem >> 3;
      int e = 8 * r + p + j;
      if (e >= S_LEN)
        cp[((size_t)(b * 8 + p) * CPROWS + r) * 8 + j] = 0;
    }
    return;
  }
  int row = bx * 4 + (threadIdx.x >> 6);   // b*4096 + t
  int l = threadIdx.x & 63;
  const float* xr = x + (size_t)row * 128;
  float x0 = xr[l], x1 = xr[l + 64];
  float s = x0 * Wu[l] + x1 * Wu[l + 64];
  #pragma unroll
  for (int m = 32; m >= 1; m >>= 1) s += __shfl_xor(s, m, 64);
  short* mrow = mx + (size_t)row * KTOT + 256;
  mrow[l]      = f2bf(x0);
  mrow[l + 64] = f2bf(x1);
  float v = s + bu[0];
  v = v > 0.0f ? v : 0.0f;
  short vb = f2bf(v);
  if (l < 8) {
    int t = row & (S_LEN - 1);
    int b = row >> 12;
    int e = (S_LEN - 1) - t;       // u_rev index of this element
    int p = l;
    if (e >= p) {
      int d = e - p;
      cp[((size_t)(b * 8 + p) * CPROWS + (d >> 3)) * 8 + (d & 7)] = vb;
    }
  }
}

// K2: pipelined Toeplitz GEMM. m[b][s][q] = sum_tau u[b][s-tau]*H[q][tau].
// 128x128 tile, BK=64. B staged in 4-slot LDS ring (swizzled), stage c+2 (the
// slot's previous readers are separated by the c-1 barrier -> race-free with
// ONE barrier/chunk). A fragments direct from global cp (parity copies make
// them aligned b128 loads), register-prefetched one chunk ahead.
// Exact vmcnt: steady in-flight = STAGE(c+2)[4] + A(c+1)[6] = 10; tail 6; 0.
// Balance remap: co-resident pair (i, i+256) has constant total work.
__global__ __launch_bounds__(256, 2) void k_conv(const short* __restrict__ cp,
                                                 const short* __restrict__ Hb,
                                                 short* __restrict__ mx) {
  __shared__ __attribute__((aligned(16))) short Bt[4][128 * 64];  // 64 KB

  int i = blockIdx.x;
  int k = (i & 255) >> 4;
  int st = (i < 256) ? (31 - k) : k;
  int rem = i & 15;
  int qt  = rem & 1;
  int b   = rem >> 1;
  int s0 = st << 7, q0 = qt << 7;

  int tid = threadIdx.x;
  int lane = tid & 63, wid = tid >> 6;
  int wr = wid >> 1, wc = wid & 1;      // wave tile 64(s) x 64(q)
  int lm = lane & 15, kg = lane >> 4;
  int l3 = lane >> 3, l7 = lane & 7;
  int lm7 = lm & 7;

  // B staging source (swizzle via pre-swizzled source col; LDS dest linear)
  const short* bSrc = Hb + (size_t)(q0 + wid * 32 + l3) * S_LEN + ((l7 ^ l3) << 3);

  // A global fragment base: element e(c,frag) = e0 + 64*c + adel; parity p
  // constant per lane; cp short-index = (b*8+p)*CPROWS*8 + (e - p).
  int e0 = (S_LEN - 1) - s0 - 64 * wr - lm + 8 * kg;
  int p  = (7 - lm) & 7;
  const short* aBase = cp + (size_t)(b * 8 + p) * CPROWS * 8 + (e0 - p);
  const int adel[6] = {0, -16, -32, -48, 32, 16};   // (mf,ks): i<4 -> (i,0); 4->(0,1); 5->(1,1)

  // B-fragment LDS offsets
  int bRow = (wc * 64 + lm) * 64;
  int bof[8];
  #pragma unroll
  for (int nf = 0; nf < 4; ++nf)
    #pragma unroll
    for (int ks = 0; ks < 2; ++ks)
      bof[nf * 2 + ks] = bRow + nf * 1024 + (((ks << 5) + (kg << 3)) ^ (lm7 << 3));

  f32x4 acc[4][4];
  #pragma unroll
  for (int ii = 0; ii < 4; ++ii)
    #pragma unroll
    for (int jn = 0; jn < 4; ++jn)
      acc[ii][jn] = (f32x4){0.0f, 0.0f, 0.0f, 0.0f};

  int nchunks = 2 * st + 2;

  auto STAGE = [&](int cc) {
    int slot = cc & 3;
    #pragma unroll
    for (int ii = 0; ii < 4; ++ii)
      gload16(bSrc + (size_t)ii * 8 * S_LEN + cc * 64, &Bt[slot][(wid * 32 + ii * 8) * 64]);
  };

  short8 Acur[6], Anxt[6];
  STAGE(0);
  STAGE(1);
  #pragma unroll
  for (int ii = 0; ii < 6; ++ii) Acur[ii] = *(const short8*)(aBase + adel[ii]);

  for (int c = 0; c < nchunks; ++c) {
    if (c + 2 < nchunks) STAGE(c + 2);
    if (c + 1 < nchunks) {
      const short* an = aBase + (c + 1) * 64;
      #pragma unroll
      for (int ii = 0; ii < 6; ++ii) Anxt[ii] = *(const short8*)(an + adel[ii]);
    }
    if (c + 2 < nchunks)      asm volatile("s_waitcnt vmcnt(10) lgkmcnt(0)\n\ts_barrier" ::: "memory");
    else if (c + 1 < nchunks) asm volatile("s_waitcnt vmcnt(6) lgkmcnt(0)\n\ts_barrier" ::: "memory");
    else                      asm volatile("s_waitcnt vmcnt(0) lgkmcnt(0)\n\ts_barrier" ::: "memory");

    const short* BtB = &Bt[c & 3][0];
    short8 Bf[8];
    #pragma unroll
    for (int ii = 0; ii < 8; ++ii) Bf[ii] = *(const short8*)(BtB + bof[ii]);
    __builtin_amdgcn_s_setprio(1);
    #pragma unroll
    for (int nf = 0; nf < 4; ++nf) {
      acc[0][nf] = __builtin_amdgcn_mfma_f32_16x16x32_bf16(Acur[0], Bf[nf * 2], acc[0][nf], 0, 0, 0);
      acc[1][nf] = __builtin_amdgcn_mfma_f32_16x16x32_bf16(Acur[1], Bf[nf * 2], acc[1][nf], 0, 0, 0);
      acc[2][nf] = __builtin_amdgcn_mfma_f32_16x16x32_bf16(Acur[2], Bf[nf * 2], acc[2][nf], 0, 0, 0);
      acc[3][nf] = __builtin_amdgcn_mfma_f32_16x16x32_bf16(Acur[3], Bf[nf * 2], acc[3][nf], 0, 0, 0);
    }
    #pragma unroll
    for (int nf = 0; nf < 4; ++nf) {
      acc[0][nf] = __builtin_amdgcn_mfma_f32_16x16x32_bf16(Acur[4], Bf[nf * 2 + 1], acc[0][nf], 0, 0, 0);
      acc[1][nf] = __builtin_amdgcn_mfma_f32_16x16x32_bf16(Acur[5], Bf[nf * 2 + 1], acc[1][nf], 0, 0, 0);
      acc[2][nf] = __builtin_amdgcn_mfma_f32_16x16x32_bf16(Acur[0], Bf[nf * 2 + 1], acc[2][nf], 0, 0, 0);
      acc[3][nf] = __builtin_amdgcn_mfma_f32_16x16x32_bf16(Acur[1], Bf[nf * 2 + 1], acc[3][nf], 0, 0, 0);
    }
    __builtin_amdgcn_s_setprio(0);
    #pragma unroll
    for (int ii = 0; ii < 6; ++ii) Acur[ii] = Anxt[ii];
    __builtin_amdgcn_sched_barrier(0);
  }

  // C/D layout: col = lane&15, row = (lane>>4)*4 + reg
  #pragma unroll
  for (int mf = 0; mf < 4; ++mf)
    #pragma unroll
    for (int nf = 0; nf < 4; ++nf)
      #pragma unroll
      for (int j = 0; j < 4; ++j) {
        int s = s0 + wr * 64 + mf * 16 + kg * 4 + j;
        int q = q0 + wc * 64 + nf * 16 + lm;
        mx[(size_t)(b * S_LEN + s) * KTOT + q] = f2bf(acc[mf][nf][j]);
      }
}

// K3: h = relu(mx @ W_h + b_h); h_n extra write for s==4095 rows.
// A (mx) staged in 4-slot LDS ring, stage c+2, one barrier/chunk (race-free).
// B (wht, 96 KB, L2-hot) fragments from global, register-prefetched 1 ahead.
__global__ __launch_bounds__(256, 2) void k_gemm2(const short* __restrict__ mx,
                                                  const short* __restrict__ wht,
                                                  const float* __restrict__ bh,
                                                  float* __restrict__ out) {
  __shared__ __attribute__((aligned(16))) short At[4][128 * 64];  // 64 KB

  int idx = blockIdx.x;       // 512 = 256 row-tiles * 2 n-tiles
  int nt = idx & 1;
  int rt = idx >> 1;
  int R0 = rt << 7;

  int tid = threadIdx.x;
  int lane = tid & 63, wid = tid >> 6;
  int wr = wid >> 1, wc = wid & 1;
  int lm = lane & 15, kg = lane >> 4;
  int l3 = lane >> 3, l7 = lane & 7;
  int lm7 = lm & 7;

  const short* aSrc  = mx  + (size_t)(R0 + wid * 32 + l3) * KTOT + ((l7 ^ l3) << 3);
  const short* bBase = wht + (size_t)(nt * 128 + wc * 64 + lm) * KTOT + 8 * kg;

  int aRow = (wr * 64 + lm) * 64;
  int aof[8];
  #pragma unroll
  for (int f = 0; f < 4; ++f)
    #pragma unroll
    for (int ks = 0; ks < 2; ++ks)
      aof[f * 2 + ks] = aRow + f * 1024 + (((ks << 5) + (kg << 3)) ^ (lm7 << 3));

  f32x4 acc[4][4];
  #pragma unroll
  for (int ii = 0; ii < 4; ++ii)
    #pragma unroll
    for (int jn = 0; jn < 4; ++jn)
      acc[ii][jn] = (f32x4){0.0f, 0.0f, 0.0f, 0.0f};

  auto STAGE = [&](int cc) {
    int slot = cc & 3;
    #pragma unroll
    for (int ii = 0; ii < 4; ++ii)
      gload16(aSrc + (size_t)ii * 8 * KTOT + cc * 64, &At[slot][(wid * 32 + ii * 8) * 64]);
  };

  short8 Bcur[8], Bnxt[8];
  STAGE(0);
  STAGE(1);
  #pragma unroll
  for (int nf = 0; nf < 4; ++nf)
    #pragma unroll
    for (int ks = 0; ks < 2; ++ks)
      Bcur[nf * 2 + ks] = *(const short8*)(bBase + nf * 16 * KTOT + 32 * ks);

  for (int c = 0; c < 6; ++c) {
    if (c + 2 < 6) STAGE(c + 2);
    if (c + 1 < 6) {
      const short* bb = bBase + (c + 1) * 64;
      #pragma unroll
      for (int nf = 0; nf < 4; ++nf)
        #pragma unroll
        for (int ks = 0; ks < 2; ++ks)
          Bnxt[nf * 2 + ks] = *(const short8*)(bb + nf * 16 * KTOT + 32 * ks);
    }
    if (c + 2 < 6)      asm volatile("s_waitcnt vmcnt(12) lgkmcnt(0)\n\ts_barrier" ::: "memory");
    else if (c + 1 < 6) asm volatile("s_waitcnt vmcnt(8) lgkmcnt(0)\n\ts_barrier" ::: "memory");
    else                asm volatile("s_waitcnt vmcnt(0) lgkmcnt(0)\n\ts_barrier" ::: "memory");

    const short* AtB = &At[c & 3][0];
    short8 Af[8];
    #pragma unroll
    for (int ii = 0; ii < 8; ++ii) Af[ii] = *(const short8*)(AtB + aof[ii]);
    __builtin_amdgcn_s_setprio(1);
    #pragma unroll
    for (int ks = 0; ks < 2; ++ks)
      #pragma unroll
      for (int mf = 0; mf < 4; ++mf)
        #pragma unroll
        for (int nf = 0; nf < 4; ++nf)
          acc[mf][nf] = __builtin_amdgcn_mfma_f32_16x16x32_bf16(Af[mf * 2 + ks], Bcur[nf * 2 + ks], acc[mf][nf], 0, 0, 0);
    __builtin_amdgcn_s_setprio(0);
    #pragma unroll
    for (int ii = 0; ii < 8; ++ii) Bcur[ii] = Bnxt[ii];
    __builtin_amdgcn_sched_barrier(0);
  }

  #pragma unroll
  for (int mf = 0; mf < 4; ++mf)
    #pragma unroll
    for (int nf = 0; nf < 4; ++nf) {
      int n = nt * 128 + wc * 64 + nf * 16 + lm;
      float bias = bh[n];
      #pragma unroll
      for (int j = 0; j < 4; ++j) {
        int R = R0 + wr * 64 + mf * 16 + kg * 4 + j;
        float v = acc[mf][nf][j] + bias;
        v = v > 0.0f ? v : 0.0f;
        out[(size_t)R * 256 + n] = v;
        if ((R & (S_LEN - 1)) == (S_LEN - 1))
          out[HN_OFF + (R >> 12) * 256 + n] = v;
      }
    }
}

extern "C" void kernel_launch(void* const* d_in, const int* in_sizes, int n_in,
                              void* d_out, int out_size, void* d_ws, size_t ws_size,
                              hipStream_t stream) {
  const float* x  = (const float*)d_in[0];
  const float* Wu = (const float*)d_in[1];
  const float* bu = (const float*)d_in[2];
  const float* Wh = (const float*)d_in[3];
  const float* bh = (const float*)d_in[4];
  const float* H  = (const float*)d_in[5];
  float* out = (float*)d_out;

  char* ws = (char*)d_ws;
  short* cp  = (short*)(ws + 131072);              // 8*8*544*8*2 = 557056 B
  short* Hb  = (short*)(ws + 688128);              // 2097152 B
  short* wht = (short*)(ws + 2785280);             // 196608 B
  short* mx  = (short*)(ws + 2981888);             // 25165824 B

  k_prep<<<12744, 256, 0, stream>>>(x, Wu, bu, H, Wh, mx, cp, Hb, wht);
  k_conv<<<512,  256, 0, stream>>>(cp, Hb, mx);
  k_gemm2<<<512, 256, 0, stream>>>(mx, wht, bh, out);
}

// Round 6
// 85.179 us; speedup vs baseline: 1.1677x; 1.1677x over previous
//
#include <hip/hip_runtime.h>

#define S_LEN 4096
#define B_SZ 8
#define KTOT 384            // M (256) + D (128)
#define CPROWS 544          // 8-elem rows per parity copy (zero-padded past 4096)
#define HN_OFF 8388608      // 8*4096*256

typedef __attribute__((ext_vector_type(8))) short short8;
typedef __attribute__((ext_vector_type(4))) float f32x4;

typedef const __attribute__((address_space(1))) unsigned int as1_u32;
typedef __attribute__((address_space(3))) unsigned int as3_u32;

__device__ __forceinline__ void gload16(const short* g, short* l) {
  __builtin_amdgcn_global_load_lds((as1_u32*)g, (as3_u32*)l, 16, 0, 0);
}

__device__ __forceinline__ short f2bf(float f) {
  union { float f; unsigned u; } v; v.f = f;
  unsigned r = v.u + 0x7FFFu + ((v.u >> 16) & 1u);
  return (short)(r >> 16);
}

// K1 fused prep:
//  blocks [0,8192):      u = relu(x@W_u+b_u) scattered into 8 parity copies cp;
//                        x -> bf16 into mx[...,256:384]
//  blocks [8192,8264):   zero the e>=4096 tail of cp
//  blocks [8264,12360):  H -> bf16
//  blocks [12360,12744): W_h^T -> bf16
__global__ __launch_bounds__(256) void k_prep(const float* __restrict__ x,
                                              const float* __restrict__ Wu,
                                              const float* __restrict__ bu,
                                              const float* __restrict__ H,
                                              const float* __restrict__ Wh,
                                              short* __restrict__ mx,
                                              short* __restrict__ cp,
                                              short* __restrict__ Hb,
                                              short* __restrict__ wht) {
  int bx = blockIdx.x;
  if (bx >= 12360) {
    int j = (bx - 12360) * 256 + threadIdx.x;
    if (j < 256 * KTOT) {
      int n = j / KTOT, k = j % KTOT;
      wht[j] = f2bf(Wh[k * 256 + n]);
    }
    return;
  }
  if (bx >= 8264) {
    int i = (bx - 8264) * 256 + threadIdx.x;
    Hb[i] = f2bf(H[i]);
    return;
  }
  if (bx >= 8192) {
    int idx = (bx - 8192) * 256 + threadIdx.x;   // b(8)*p(8)*r(36)*j(8)
    if (idx < 18432) {
      int j = idx & 7;
      int r = 508 + ((idx >> 3) % 36);
      int rem = (idx >> 3) / 36;
      int p = rem & 7;
      int b = rem >> 3;
      int e = 8 * r + p + j;
      if (e >= S_LEN)
        cp[((size_t)(b * 8 + p) * CPROWS + r) * 8 + j] = 0;
    }
    return;
  }
  int row = bx * 4 + (threadIdx.x >> 6);   // b*4096 + t
  int l = threadIdx.x & 63;
  const float* xr = x + (size_t)row * 128;
  float x0 = xr[l], x1 = xr[l + 64];
  float s = x0 * Wu[l] + x1 * Wu[l + 64];
  #pragma unroll
  for (int m = 32; m >= 1; m >>= 1) s += __shfl_xor(s, m, 64);
  short* mrow = mx + (size_t)row * KTOT + 256;
  mrow[l]      = f2bf(x0);
  mrow[l + 64] = f2bf(x1);
  float v = s + bu[0];
  v = v > 0.0f ? v : 0.0f;
  short vb = f2bf(v);
  if (l < 8) {
    int t = row & (S_LEN - 1);
    int b = row >> 12;
    int e = (S_LEN - 1) - t;       // u_rev index of this element
    int p = l;
    if (e >= p) {
      int d = e - p;
      cp[((size_t)(b * 8 + p) * CPROWS + (d >> 3)) * 8 + (d & 7)] = vb;
    }
  }
}

// K2: pipelined Toeplitz GEMM, m[b][s][q] = sum_tau u[b][s-tau]*H[q][tau].
// 256 blocks; block (k,qt,b) computes tiles st=31-k then st=k sequentially
// -> exactly 68 chunks/block; LDS 80.6KB forces 1 block/CU -> perfect balance
// with no placement assumptions. B in 4-slot swizzled LDS ring; A window in
// 4-slot LDS ring with rotation swizzle (conflict-free), staged via
// pre-permuted source parity. One barrier/chunk, counted vmcnt (5 loads/STAGE).
__global__ __launch_bounds__(256) void k_conv(const short* __restrict__ cp,
                                              const short* __restrict__ Hb,
                                              short* __restrict__ mx) {
  __shared__ __attribute__((aligned(16))) short Bt[4][128 * 64];  // 64 KB
  __shared__ __attribute__((aligned(16))) short Aw[4][2080];      // 16.64 KB (pad -> 1 blk/CU)

  int i = blockIdx.x;                 // 256 blocks
  int kk = i >> 4;
  int qt = i & 1;
  int b  = (i >> 1) & 7;
  int q0 = qt << 7;

  int tid = threadIdx.x;
  int lane = tid & 63, wid = tid >> 6;
  int wr = wid >> 1, wc = wid & 1;      // wave tile 64(s) x 64(q)
  int lm = lane & 15, kg = lane >> 4;
  int l3 = lane >> 3, l7 = lane & 7;
  int lm7 = lm & 7;

  // B staging source (swizzle via pre-swizzled source col; LDS dest linear)
  const short* bSrc = Hb + (size_t)(q0 + wid * 32 + l3) * S_LEN + ((l7 ^ l3) << 3);

  // A parity base: source parity pre-permuted so LDS unit v holds data unit
  // sigma^-1(v); reads use sigma(u). sigma(u) = (u&~7)|((u+(u>>3))&7).
  const size_t aPar = (size_t)(b * 8 + ((l7 - l3) & 7)) * CPROWS * 8;

  // A-frag swizzled offsets (window-relative, phase-independent)
  int dbase = 127 - 64 * wr - lm + 8 * kg;
  const int adel[6] = {0, -16, -32, -48, 32, 16};   // (mf,ks): i<4->(i,0); 4->(0,1); 5->(1,1)
  int aof[6];
  #pragma unroll
  for (int ii = 0; ii < 6; ++ii) {
    int u = dbase + adel[ii];
    aof[ii] = ((u & ~7) | ((u + (u >> 3)) & 7)) << 3;   // shorts
  }

  // B-fragment LDS offsets
  int bRow = (wc * 64 + lm) * 64;
  int bof[8];
  #pragma unroll
  for (int nf = 0; nf < 4; ++nf)
    #pragma unroll
    for (int ks = 0; ks < 2; ++ks)
      bof[nf * 2 + ks] = bRow + nf * 1024 + (((ks << 5) + (kg << 3)) ^ (lm7 << 3));

  for (int ph = 0; ph < 2; ++ph) {
    int st = ph ? kk : (31 - kk);
    int s0 = st << 7;
    int asbase = 496 - 16 * st;
    const short* aSrc = cp + aPar + (size_t)(asbase + wid * 8 + l3) * 8;
    int nchunks = 2 * st + 2;

    f32x4 acc[4][4];
    #pragma unroll
    for (int ii = 0; ii < 4; ++ii)
      #pragma unroll
      for (int jn = 0; jn < 4; ++jn)
        acc[ii][jn] = (f32x4){0.0f, 0.0f, 0.0f, 0.0f};

    auto STAGE = [&](int cc) {
      int slot = cc & 3;
      #pragma unroll
      for (int ii = 0; ii < 4; ++ii)
        gload16(bSrc + (size_t)ii * 8 * S_LEN + cc * 64, &Bt[slot][(wid * 32 + ii * 8) * 64]);
      gload16(aSrc + cc * 64, &Aw[slot][wid * 512]);
    };

    STAGE(0);
    STAGE(1);

    for (int c = 0; c < nchunks; ++c) {
      if (c + 2 < nchunks) {
        STAGE(c + 2);
        asm volatile("s_waitcnt vmcnt(10) lgkmcnt(0)\n\ts_barrier" ::: "memory");
      } else if (c + 1 < nchunks) {
        asm volatile("s_waitcnt vmcnt(5) lgkmcnt(0)\n\ts_barrier" ::: "memory");
      } else {
        asm volatile("s_waitcnt vmcnt(0) lgkmcnt(0)\n\ts_barrier" ::: "memory");
      }
      const short* AwB = &Aw[c & 3][0];
      const short* BtB = &Bt[c & 3][0];
      short8 A[6];
      #pragma unroll
      for (int ii = 0; ii < 6; ++ii) A[ii] = *(const short8*)(AwB + aof[ii]);
      short8 Bf[8];
      #pragma unroll
      for (int ii = 0; ii < 8; ++ii) Bf[ii] = *(const short8*)(BtB + bof[ii]);
      __builtin_amdgcn_s_setprio(1);
      #pragma unroll
      for (int nf = 0; nf < 4; ++nf) {
        acc[0][nf] = __builtin_amdgcn_mfma_f32_16x16x32_bf16(A[0], Bf[nf * 2], acc[0][nf], 0, 0, 0);
        acc[1][nf] = __builtin_amdgcn_mfma_f32_16x16x32_bf16(A[1], Bf[nf * 2], acc[1][nf], 0, 0, 0);
        acc[2][nf] = __builtin_amdgcn_mfma_f32_16x16x32_bf16(A[2], Bf[nf * 2], acc[2][nf], 0, 0, 0);
        acc[3][nf] = __builtin_amdgcn_mfma_f32_16x16x32_bf16(A[3], Bf[nf * 2], acc[3][nf], 0, 0, 0);
      }
      #pragma unroll
      for (int nf = 0; nf < 4; ++nf) {
        acc[0][nf] = __builtin_amdgcn_mfma_f32_16x16x32_bf16(A[4], Bf[nf * 2 + 1], acc[0][nf], 0, 0, 0);
        acc[1][nf] = __builtin_amdgcn_mfma_f32_16x16x32_bf16(A[5], Bf[nf * 2 + 1], acc[1][nf], 0, 0, 0);
        acc[2][nf] = __builtin_amdgcn_mfma_f32_16x16x32_bf16(A[0], Bf[nf * 2 + 1], acc[2][nf], 0, 0, 0);
        acc[3][nf] = __builtin_amdgcn_mfma_f32_16x16x32_bf16(A[1], Bf[nf * 2 + 1], acc[3][nf], 0, 0, 0);
      }
      __builtin_amdgcn_s_setprio(0);
    }

    // all waves done reading this phase's LDS before next phase's staging
    asm volatile("s_waitcnt lgkmcnt(0)\n\ts_barrier" ::: "memory");

    // C/D layout: col = lane&15, row = (lane>>4)*4 + reg
    #pragma unroll
    for (int mf = 0; mf < 4; ++mf)
      #pragma unroll
      for (int nf = 0; nf < 4; ++nf)
        #pragma unroll
        for (int j = 0; j < 4; ++j) {
          int s = s0 + wr * 64 + mf * 16 + kg * 4 + j;
          int q = q0 + wc * 64 + nf * 16 + lm;
          mx[(size_t)(b * S_LEN + s) * KTOT + q] = f2bf(acc[mf][nf][j]);
        }
  }
}

// K3: h = relu(mx @ W_h + b_h); h_n extra write for s==4095 rows.
// A (mx) staged in 4-slot LDS ring, stage c+2, one barrier/chunk (race-free).
// B (wht, 96 KB, L2-hot) fragments from global, register-prefetched 1 ahead.
__global__ __launch_bounds__(256, 2) void k_gemm2(const short* __restrict__ mx,
                                                  const short* __restrict__ wht,
                                                  const float* __restrict__ bh,
                                                  float* __restrict__ out) {
  __shared__ __attribute__((aligned(16))) short At[4][128 * 64];  // 64 KB

  int idx = blockIdx.x;       // 512 = 256 row-tiles * 2 n-tiles
  int nt = idx & 1;
  int rt = idx >> 1;
  int R0 = rt << 7;

  int tid = threadIdx.x;
  int lane = tid & 63, wid = tid >> 6;
  int wr = wid >> 1, wc = wid & 1;
  int lm = lane & 15, kg = lane >> 4;
  int l3 = lane >> 3, l7 = lane & 7;
  int lm7 = lm & 7;

  const short* aSrc  = mx  + (size_t)(R0 + wid * 32 + l3) * KTOT + ((l7 ^ l3) << 3);
  const short* bBase = wht + (size_t)(nt * 128 + wc * 64 + lm) * KTOT + 8 * kg;

  int aRow = (wr * 64 + lm) * 64;
  int aof[8];
  #pragma unroll
  for (int f = 0; f < 4; ++f)
    #pragma unroll
    for (int ks = 0; ks < 2; ++ks)
      aof[f * 2 + ks] = aRow + f * 1024 + (((ks << 5) + (kg << 3)) ^ (lm7 << 3));

  f32x4 acc[4][4];
  #pragma unroll
  for (int ii = 0; ii < 4; ++ii)
    #pragma unroll
    for (int jn = 0; jn < 4; ++jn)
      acc[ii][jn] = (f32x4){0.0f, 0.0f, 0.0f, 0.0f};

  auto STAGE = [&](int cc) {
    int slot = cc & 3;
    #pragma unroll
    for (int ii = 0; ii < 4; ++ii)
      gload16(aSrc + (size_t)ii * 8 * KTOT + cc * 64, &At[slot][(wid * 32 + ii * 8) * 64]);
  };

  short8 Bcur[8], Bnxt[8];
  STAGE(0);
  STAGE(1);
  #pragma unroll
  for (int nf = 0; nf < 4; ++nf)
    #pragma unroll
    for (int ks = 0; ks < 2; ++ks)
      Bcur[nf * 2 + ks] = *(const short8*)(bBase + nf * 16 * KTOT + 32 * ks);

  for (int c = 0; c < 6; ++c) {
    if (c + 2 < 6) STAGE(c + 2);
    if (c + 1 < 6) {
      const short* bb = bBase + (c + 1) * 64;
      #pragma unroll
      for (int nf = 0; nf < 4; ++nf)
        #pragma unroll
        for (int ks = 0; ks < 2; ++ks)
          Bnxt[nf * 2 + ks] = *(const short8*)(bb + nf * 16 * KTOT + 32 * ks);
    }
    if (c + 2 < 6)      asm volatile("s_waitcnt vmcnt(12) lgkmcnt(0)\n\ts_barrier" ::: "memory");
    else if (c + 1 < 6) asm volatile("s_waitcnt vmcnt(8) lgkmcnt(0)\n\ts_barrier" ::: "memory");
    else                asm volatile("s_waitcnt vmcnt(0) lgkmcnt(0)\n\ts_barrier" ::: "memory");

    const short* AtB = &At[c & 3][0];
    short8 Af[8];
    #pragma unroll
    for (int ii = 0; ii < 8; ++ii) Af[ii] = *(const short8*)(AtB + aof[ii]);
    __builtin_amdgcn_s_setprio(1);
    #pragma unroll
    for (int ks = 0; ks < 2; ++ks)
      #pragma unroll
      for (int mf = 0; mf < 4; ++mf)
        #pragma unroll
        for (int nf = 0; nf < 4; ++nf)
          acc[mf][nf] = __builtin_amdgcn_mfma_f32_16x16x32_bf16(Af[mf * 2 + ks], Bcur[nf * 2 + ks], acc[mf][nf], 0, 0, 0);
    __builtin_amdgcn_s_setprio(0);
    #pragma unroll
    for (int ii = 0; ii < 8; ++ii) Bcur[ii] = Bnxt[ii];
  }

  #pragma unroll
  for (int mf = 0; mf < 4; ++mf)
    #pragma unroll
    for (int nf = 0; nf < 4; ++nf) {
      int n = nt * 128 + wc * 64 + nf * 16 + lm;
      float bias = bh[n];
      #pragma unroll
      for (int j = 0; j < 4; ++j) {
        int R = R0 + wr * 64 + mf * 16 + kg * 4 + j;
        float v = acc[mf][nf][j] + bias;
        v = v > 0.0f ? v : 0.0f;
        out[(size_t)R * 256 + n] = v;
        if ((R & (S_LEN - 1)) == (S_LEN - 1))
          out[HN_OFF + (R >> 12) * 256 + n] = v;
      }
    }
}

extern "C" void kernel_launch(void* const* d_in, const int* in_sizes, int n_in,
                              void* d_out, int out_size, void* d_ws, size_t ws_size,
                              hipStream_t stream) {
  const float* x  = (const float*)d_in[0];
  const float* Wu = (const float*)d_in[1];
  const float* bu = (const float*)d_in[2];
  const float* Wh = (const float*)d_in[3];
  const float* bh = (const float*)d_in[4];
  const float* H  = (const float*)d_in[5];
  float* out = (float*)d_out;

  char* ws = (char*)d_ws;
  short* cp  = (short*)(ws + 131072);              // 8*8*544*8*2 = 557056 B
  short* Hb  = (short*)(ws + 688128);              // 2097152 B
  short* wht = (short*)(ws + 2785280);             // 196608 B
  short* mx  = (short*)(ws + 2981888);             // 25165824 B

  k_prep<<<12744, 256, 0, stream>>>(x, Wu, bu, H, Wh, mx, cp, Hb, wht);
  k_conv<<<256,  256, 0, stream>>>(cp, Hb, mx);
  k_gemm2<<<512, 256, 0, stream>>>(mx, wht, bh, out);
}